// Round 1
// baseline (1368.846 us; speedup 1.0000x reference)
//
#include <hip/hip_runtime.h>

#define HEADS 8
#define CPH 32
#define LORA_SCALE 4.0f
#define ATT_SCALE 8.0f
#define NEG_SLOPE 0.2f

// ---------- prep: Weff = W + LORA_SCALE * B@A ; eff att vectors ----------
__global__ void prep_kernel(const float* __restrict__ W, const float* __restrict__ A,
                            const float* __restrict__ B,
                            const float* __restrict__ att_s, const float* __restrict__ att_d,
                            const float* __restrict__ As, const float* __restrict__ Bs,
                            const float* __restrict__ Ad, const float* __restrict__ Bd,
                            float* __restrict__ Weff, float* __restrict__ effS,
                            float* __restrict__ effD)
{
    int i = blockIdx.x * blockDim.x + threadIdx.x;   // 65536 total
    int r = i >> 8, c = i & 255;
    float acc = W[i];
    #pragma unroll
    for (int k = 0; k < 8; k++) acc += LORA_SCALE * B[r * 8 + k] * A[k * 256 + c];
    Weff[i] = acc;
    if (i < 256) {
        int c2 = i & 31;
        float es = att_s[i], ed = att_d[i];
        #pragma unroll
        for (int k = 0; k < 4; k++) {
            es += ATT_SCALE * Bs[k] * As[k * 32 + c2];
            ed += ATT_SCALE * Bd[k] * Ad[k * 32 + c2];
        }
        effS[i] = es;
        effD[i] = ed;
    }
}

// ---------- fp32 GEMM: C[m,n] = sum_k A[m,k] * W[n,k]  (K = Nc = 256) ----------
#define GT 64
#define GK 16
__global__ __launch_bounds__(256) void gemm_tn(const float* __restrict__ A,
                                               const float* __restrict__ W,
                                               float* __restrict__ C, int M)
{
    __shared__ float As[GK][GT + 1];
    __shared__ float Ws[GK][GT + 1];
    const int K = 256, Nc = 256;
    int tid = threadIdx.x;
    int tx = tid & 15, ty = tid >> 4;
    int row0 = blockIdx.y * GT, col0 = blockIdx.x * GT;
    float acc[4][4] = {};
    for (int k0 = 0; k0 < K; k0 += GK) {
        int kk = tid & 15;
        int rb = tid >> 4;
        #pragma unroll
        for (int j = 0; j < 4; j++) {
            int r = rb + j * 16;
            int gr = row0 + r;
            As[kk][r] = (gr < M) ? A[gr * K + k0 + kk] : 0.0f;
            Ws[kk][r] = W[(col0 + r) * K + k0 + kk];
        }
        __syncthreads();
        #pragma unroll
        for (int k = 0; k < GK; k++) {
            float av[4], bv[4];
            #pragma unroll
            for (int i = 0; i < 4; i++) av[i] = As[k][ty * 4 + i];
            #pragma unroll
            for (int j = 0; j < 4; j++) bv[j] = Ws[k][tx * 4 + j];
            #pragma unroll
            for (int i = 0; i < 4; i++)
                #pragma unroll
                for (int j = 0; j < 4; j++)
                    acc[i][j] += av[i] * bv[j];
        }
        __syncthreads();
    }
    #pragma unroll
    for (int i = 0; i < 4; i++) {
        int gr = row0 + ty * 4 + i;
        if (gr >= M) continue;
        #pragma unroll
        for (int j = 0; j < 4; j++)
            C[gr * Nc + col0 + tx * 4 + j] = acc[i][j];
    }
}

// ---------- per-node attention scores ----------
__global__ void node_scores(const float* __restrict__ xp,
                            const float* __restrict__ effS, const float* __restrict__ effD,
                            float* __restrict__ ssrc, float* __restrict__ sdst, int N)
{
    int idx = blockIdx.x * blockDim.x + threadIdx.x;  // N*8
    if (idx >= N * 8) return;
    int n = idx >> 3, h = idx & 7;
    const float* v = xp + n * 256 + h * 32;
    const float* es = effS + h * 32;
    const float* ed = effD + h * 32;
    float as = 0.f, ad = 0.f;
    #pragma unroll
    for (int c = 0; c < 32; c++) {
        float xv = v[c];
        as += xv * es[c];
        ad += xv * ed[c];
    }
    ssrc[idx] = as;
    sdst[idx] = ad;
}

// ---------- edge pass 1: unnormalized weights + denominators ----------
__global__ void edge_alpha(const int* __restrict__ ei, int E_real, int E_total,
                           const float* __restrict__ ssrc, const float* __restrict__ sdst,
                           float* __restrict__ ew, float* __restrict__ den)
{
    int idx = blockIdx.x * blockDim.x + threadIdx.x;  // E_total*8
    if (idx >= E_total * 8) return;
    int e = idx >> 3, h = idx & 7;
    int s, d;
    if (e < E_real) { s = ei[e]; d = ei[E_real + e]; }
    else            { s = d = e - E_real; }
    float al = ssrc[d * 8 + h] + sdst[s * 8 + h];
    al = al > 0.f ? al : NEG_SLOPE * al;
    float w = __expf(al);
    ew[idx] = w;
    atomicAdd(&den[d * 8 + h], w);
}

// ---------- edge pass 2: scatter-aggregate messages (64 lanes per edge) ----------
__global__ void edge_agg(const int* __restrict__ ei, int E_real, int E_total,
                         const float* __restrict__ xp, const float* __restrict__ ew,
                         const float* __restrict__ den, float* __restrict__ out)
{
    int gid = blockIdx.x * blockDim.x + threadIdx.x;
    int e = gid >> 6;
    if (e >= E_total) return;
    int lane = gid & 63;
    int s, d;
    if (e < E_real) { s = ei[e]; d = ei[E_real + e]; }
    else            { s = d = e - E_real; }
    int h = lane >> 3;  // (lane*4)/32
    float a = ew[e * 8 + h] / den[d * 8 + h];
    const float4 v = *(const float4*)(xp + s * 256 + lane * 4);
    float* o = out + d * 256 + lane * 4;
    atomicAdd(o + 0, v.x * a);
    atomicAdd(o + 1, v.y * a);
    atomicAdd(o + 2, v.z * a);
    atomicAdd(o + 3, v.w * a);
}

// ---------- elementwise elu ----------
__global__ void elu_kernel(float* __restrict__ x, int n)
{
    int i = blockIdx.x * blockDim.x + threadIdx.x;
    if (i >= n) return;
    float v = x[i];
    x[i] = v > 0.f ? v : (__expf(v) - 1.0f);
}

// ---------- head-mean for layer-1 output ----------
__global__ void mean_heads(const float* __restrict__ o1, float* __restrict__ y, int N)
{
    int i = blockIdx.x * blockDim.x + threadIdx.x;  // N*32
    if (i >= N * 32) return;
    int n = i >> 5, c = i & 31;
    float s = 0.f;
    #pragma unroll
    for (int h = 0; h < 8; h++) s += o1[n * 256 + h * 32 + c];
    y[i] = 0.125f * s;
}

extern "C" void kernel_launch(void* const* d_in, const int* in_sizes, int n_in,
                              void* d_out, int out_size, void* d_ws, size_t ws_size,
                              hipStream_t stream)
{
    const float* x  = (const float*)d_in[0];
    const int*   ei = (const int*)d_in[1];
    const float* W0 = (const float*)d_in[2];
    const float* A0 = (const float*)d_in[3];
    const float* B0 = (const float*)d_in[4];
    const float* att_s0 = (const float*)d_in[5];
    const float* att_d0 = (const float*)d_in[6];
    const float* As0 = (const float*)d_in[7];
    const float* Bs0 = (const float*)d_in[8];
    const float* Ad0 = (const float*)d_in[9];
    const float* Bd0 = (const float*)d_in[10];
    const float* W1 = (const float*)d_in[11];
    const float* A1 = (const float*)d_in[12];
    const float* B1 = (const float*)d_in[13];
    const float* att_s1 = (const float*)d_in[14];
    const float* att_d1 = (const float*)d_in[15];
    const float* As1 = (const float*)d_in[16];
    const float* Bs1 = (const float*)d_in[17];
    const float* Ad1 = (const float*)d_in[18];
    const float* Bd1 = (const float*)d_in[19];

    const int N = in_sizes[0] / 256;      // 10000
    const int E_real = in_sizes[1] / 2;   // 160000
    const int E_total = E_real + N;       // 170000

    float* ws = (float*)d_ws;
    float* Weff0 = ws;                    // 65536
    float* Weff1 = ws + 65536;            // 65536
    float* effS0 = ws + 131072;           // 256
    float* effD0 = effS0 + 256;
    float* effS1 = effS0 + 512;
    float* effD1 = effS0 + 768;
    float* xp   = ws + 132096;            // N*256
    float* hb   = xp + 2560000;           // N*256
    float* o1   = hb + 2560000;           // N*256
    float* ssrc = o1 + 2560000;           // N*8
    float* sdst = ssrc + 80000;           // N*8
    float* den  = sdst + 80000;           // N*8
    float* ew   = den + 80000;            // E_total*8

    prep_kernel<<<256, 256, 0, stream>>>(W0, A0, B0, att_s0, att_d0, As0, Bs0, Ad0, Bd0,
                                         Weff0, effS0, effD0);
    prep_kernel<<<256, 256, 0, stream>>>(W1, A1, B1, att_s1, att_d1, As1, Bs1, Ad1, Bd1,
                                         Weff1, effS1, effD1);

    dim3 gg(4, (N + GT - 1) / GT);

    // ---------------- layer 0 ----------------
    gemm_tn<<<gg, 256, 0, stream>>>(x, Weff0, xp, N);
    node_scores<<<(N * 8 + 255) / 256, 256, 0, stream>>>(xp, effS0, effD0, ssrc, sdst, N);
    hipMemsetAsync(den, 0, (size_t)N * 8 * sizeof(float), stream);
    edge_alpha<<<(E_total * 8 + 255) / 256, 256, 0, stream>>>(ei, E_real, E_total, ssrc, sdst, ew, den);
    hipMemsetAsync(hb, 0, (size_t)N * 256 * sizeof(float), stream);
    edge_agg<<<(E_total * 64 + 255) / 256, 256, 0, stream>>>(ei, E_real, E_total, xp, ew, den, hb);
    elu_kernel<<<(N * 256 + 255) / 256, 256, 0, stream>>>(hb, N * 256);

    // ---------------- layer 1 ----------------
    gemm_tn<<<gg, 256, 0, stream>>>(hb, Weff1, xp, N);
    node_scores<<<(N * 8 + 255) / 256, 256, 0, stream>>>(xp, effS1, effD1, ssrc, sdst, N);
    hipMemsetAsync(den, 0, (size_t)N * 8 * sizeof(float), stream);
    edge_alpha<<<(E_total * 8 + 255) / 256, 256, 0, stream>>>(ei, E_real, E_total, ssrc, sdst, ew, den);
    hipMemsetAsync(o1, 0, (size_t)N * 256 * sizeof(float), stream);
    edge_agg<<<(E_total * 64 + 255) / 256, 256, 0, stream>>>(ei, E_real, E_total, xp, ew, den, o1);
    mean_heads<<<(N * 32 + 255) / 256, 256, 0, stream>>>(o1, (float*)d_out, N);
}

// Round 2
// 315.903 us; speedup vs baseline: 4.3331x; 4.3331x over previous
//
#include <hip/hip_runtime.h>

#define HEADS 8
#define LORA_SCALE 4.0f
#define ATT_SCALE 8.0f
#define NEG_SLOPE 0.2f

// ---------- prep: Weff = W + LORA_SCALE * B@A ; eff att vectors ----------
__global__ void prep_kernel(const float* __restrict__ W, const float* __restrict__ A,
                            const float* __restrict__ B,
                            const float* __restrict__ att_s, const float* __restrict__ att_d,
                            const float* __restrict__ As, const float* __restrict__ Bs,
                            const float* __restrict__ Ad, const float* __restrict__ Bd,
                            float* __restrict__ Weff, float* __restrict__ effS,
                            float* __restrict__ effD)
{
    int i = blockIdx.x * blockDim.x + threadIdx.x;   // 65536 total
    int r = i >> 8, c = i & 255;
    float acc = W[i];
    #pragma unroll
    for (int k = 0; k < 8; k++) acc += LORA_SCALE * B[r * 8 + k] * A[k * 256 + c];
    Weff[i] = acc;
    if (i < 256) {
        int c2 = i & 31;
        float es = att_s[i], ed = att_d[i];
        #pragma unroll
        for (int k = 0; k < 4; k++) {
            es += ATT_SCALE * Bs[k] * As[k * 32 + c2];
            ed += ATT_SCALE * Bd[k] * Ad[k * 32 + c2];
        }
        effS[i] = es;
        effD[i] = ed;
    }
}

// ---------- fp32 GEMM: C[m,n] = sum_k A[m,k] * W[n,k]  (K = Nc = 256) ----------
#define GT 64
#define GK 16
__global__ __launch_bounds__(256) void gemm_tn(const float* __restrict__ A,
                                               const float* __restrict__ W,
                                               float* __restrict__ C, int M)
{
    __shared__ float As[GK][GT + 1];
    __shared__ float Ws[GK][GT + 1];
    const int K = 256, Nc = 256;
    int tid = threadIdx.x;
    int tx = tid & 15, ty = tid >> 4;
    int row0 = blockIdx.y * GT, col0 = blockIdx.x * GT;
    float acc[4][4] = {};
    for (int k0 = 0; k0 < K; k0 += GK) {
        int kk = tid & 15;
        int rb = tid >> 4;
        #pragma unroll
        for (int j = 0; j < 4; j++) {
            int r = rb + j * 16;
            int gr = row0 + r;
            As[kk][r] = (gr < M) ? A[gr * K + k0 + kk] : 0.0f;
            Ws[kk][r] = W[(col0 + r) * K + k0 + kk];
        }
        __syncthreads();
        #pragma unroll
        for (int k = 0; k < GK; k++) {
            float av[4], bv[4];
            #pragma unroll
            for (int i = 0; i < 4; i++) av[i] = As[k][ty * 4 + i];
            #pragma unroll
            for (int j = 0; j < 4; j++) bv[j] = Ws[k][tx * 4 + j];
            #pragma unroll
            for (int i = 0; i < 4; i++)
                #pragma unroll
                for (int j = 0; j < 4; j++)
                    acc[i][j] += av[i] * bv[j];
        }
        __syncthreads();
    }
    #pragma unroll
    for (int i = 0; i < 4; i++) {
        int gr = row0 + ty * 4 + i;
        if (gr >= M) continue;
        #pragma unroll
        for (int j = 0; j < 4; j++)
            C[gr * Nc + col0 + tx * 4 + j] = acc[i][j];
    }
}

// ---------- per-node attention scores ----------
__global__ void node_scores(const float* __restrict__ xp,
                            const float* __restrict__ effS, const float* __restrict__ effD,
                            float* __restrict__ ssrc, float* __restrict__ sdst, int N)
{
    int idx = blockIdx.x * blockDim.x + threadIdx.x;  // N*8
    if (idx >= N * 8) return;
    int n = idx >> 3, h = idx & 7;
    const float* v = xp + n * 256 + h * 32;
    const float* es = effS + h * 32;
    const float* ed = effD + h * 32;
    float as = 0.f, ad = 0.f;
    #pragma unroll
    for (int c = 0; c < 32; c++) {
        float xv = v[c];
        as += xv * es[c];
        ad += xv * ed[c];
    }
    ssrc[idx] = as;
    sdst[idx] = ad;
}

// ---------- CSR build: histogram ----------
__global__ void hist_kernel(const int* __restrict__ ei, int E_real, int E_total,
                            int* __restrict__ deg)
{
    int e = blockIdx.x * blockDim.x + threadIdx.x;
    if (e >= E_total) return;
    int d = (e < E_real) ? ei[E_real + e] : (e - E_real);
    atomicAdd(&deg[d], 1);
}

// ---------- CSR build: single-block exclusive scan over deg (N ~ 10000) ----------
__global__ __launch_bounds__(256) void scan_kernel(const int* __restrict__ deg,
                                                   int* __restrict__ rowptr,
                                                   int* __restrict__ cursor, int N)
{
    __shared__ int sums[256];
    int t = threadIdx.x;
    int per = (N + 255) / 256;
    int start = t * per;
    int end = start + per; if (end > N) end = N; if (start > N) start = N;
    int s = 0;
    for (int i = start; i < end; i++) s += deg[i];
    sums[t] = s;
    __syncthreads();
    for (int off = 1; off < 256; off <<= 1) {
        int v = (t >= off) ? sums[t - off] : 0;
        __syncthreads();
        sums[t] += v;
        __syncthreads();
    }
    int prefix = (t == 0) ? 0 : sums[t - 1];
    for (int i = start; i < end; i++) {
        rowptr[i] = prefix;
        cursor[i] = prefix;
        prefix += deg[i];
    }
    if (t == 255) rowptr[N] = sums[255];
}

// ---------- CSR build: fill src lists ----------
__global__ void fill_csr(const int* __restrict__ ei, int E_real, int E_total,
                         int* __restrict__ cursor, int* __restrict__ csr_src)
{
    int e = blockIdx.x * blockDim.x + threadIdx.x;
    if (e >= E_total) return;
    int s, d;
    if (e < E_real) { s = ei[e]; d = ei[E_real + e]; }
    else            { s = d = e - E_real; }
    int pos = atomicAdd(&cursor[d], 1);
    csr_src[pos] = s;
}

// ---------- gather-aggregate: one wave per destination node ----------
// mode 0: write 256ch raw; mode 1: write 256ch with ELU; mode 2: head-mean -> 32ch
__global__ __launch_bounds__(256) void csr_agg(const int* __restrict__ rowptr,
                                               const int* __restrict__ csr_src,
                                               const float* __restrict__ xp,
                                               const float* __restrict__ ssrc,
                                               const float* __restrict__ sdst,
                                               float* __restrict__ out, int N, int mode)
{
    int gid = blockIdx.x * blockDim.x + threadIdx.x;
    int d = gid >> 6;
    if (d >= N) return;
    int lane = threadIdx.x & 63;
    int begin = rowptr[d], end = rowptr[d + 1];

    // ---- pass 1: softmax denominator per head ----
    int h8 = lane & 7;          // head owned in pass 1
    int slot = lane >> 3;       // edge slot (8 edges in flight)
    float ssrc_h8 = ssrc[d * 8 + h8];
    float den_part = 0.f;
    for (int i = begin + slot; i < end; i += 8) {
        int s = csr_src[i];
        float al = ssrc_h8 + sdst[s * 8 + h8];
        al = al > 0.f ? al : NEG_SLOPE * al;
        den_part += __expf(al);
    }
    den_part += __shfl_xor(den_part, 8);
    den_part += __shfl_xor(den_part, 16);
    den_part += __shfl_xor(den_part, 32);
    // den for head h is now in every lane with (lane&7)==h; fetch den for my value-head
    int h4 = lane >> 3;         // head owned in pass 2 (channels lane*4 .. lane*4+3)
    float den_h4 = __shfl(den_part, h4);
    float ssrc_h4 = ssrc[d * 8 + h4];

    // ---- pass 2: weighted gather-accumulate ----
    float ax = 0.f, ay = 0.f, az = 0.f, aw = 0.f;
    for (int i = begin; i < end; i++) {
        int s = csr_src[i];
        float al = ssrc_h4 + sdst[s * 8 + h4];
        al = al > 0.f ? al : NEG_SLOPE * al;
        float a = __expf(al) / den_h4;
        const float4 v = *(const float4*)(xp + s * 256 + lane * 4);
        ax += v.x * a; ay += v.y * a; az += v.z * a; aw += v.w * a;
    }

    if (mode == 2) {
        // head-mean: reduce across the 8 head groups (lane bits 3..5)
        #pragma unroll
        for (int m = 8; m <= 32; m <<= 1) {
            ax += __shfl_xor(ax, m);
            ay += __shfl_xor(ay, m);
            az += __shfl_xor(az, m);
            aw += __shfl_xor(aw, m);
        }
        if (lane < 8) {
            float4 r = { ax * 0.125f, ay * 0.125f, az * 0.125f, aw * 0.125f };
            *(float4*)(out + d * 32 + lane * 4) = r;
        }
        return;
    }
    if (mode == 1) {
        ax = ax > 0.f ? ax : (__expf(ax) - 1.f);
        ay = ay > 0.f ? ay : (__expf(ay) - 1.f);
        az = az > 0.f ? az : (__expf(az) - 1.f);
        aw = aw > 0.f ? aw : (__expf(aw) - 1.f);
    }
    float4 r = { ax, ay, az, aw };
    *(float4*)(out + d * 256 + lane * 4) = r;
}

extern "C" void kernel_launch(void* const* d_in, const int* in_sizes, int n_in,
                              void* d_out, int out_size, void* d_ws, size_t ws_size,
                              hipStream_t stream)
{
    const float* x  = (const float*)d_in[0];
    const int*   ei = (const int*)d_in[1];
    const float* W0 = (const float*)d_in[2];
    const float* A0 = (const float*)d_in[3];
    const float* B0 = (const float*)d_in[4];
    const float* att_s0 = (const float*)d_in[5];
    const float* att_d0 = (const float*)d_in[6];
    const float* As0 = (const float*)d_in[7];
    const float* Bs0 = (const float*)d_in[8];
    const float* Ad0 = (const float*)d_in[9];
    const float* Bd0 = (const float*)d_in[10];
    const float* W1 = (const float*)d_in[11];
    const float* A1 = (const float*)d_in[12];
    const float* B1 = (const float*)d_in[13];
    const float* att_s1 = (const float*)d_in[14];
    const float* att_d1 = (const float*)d_in[15];
    const float* As1 = (const float*)d_in[16];
    const float* Bs1 = (const float*)d_in[17];
    const float* Ad1 = (const float*)d_in[18];
    const float* Bd1 = (const float*)d_in[19];

    const int N = in_sizes[0] / 256;      // 10000
    const int E_real = in_sizes[1] / 2;   // 160000
    const int E_total = E_real + N;       // 170000

    float* ws = (float*)d_ws;
    float* Weff0 = ws;                    // 65536
    float* Weff1 = ws + 65536;            // 65536
    float* effS0 = ws + 131072;           // 4*256
    float* effD0 = effS0 + 256;
    float* effS1 = effS0 + 512;
    float* effD1 = effS0 + 768;
    float* xp   = ws + 132096;            // N*256
    float* hb   = xp + 2560000;           // N*256
    float* ssrc = hb + 2560000;           // N*8
    float* sdst = ssrc + 80000;           // N*8
    int*   deg     = (int*)(sdst + 80000);   // N
    int*   rowptr  = deg + 10016;            // N+1
    int*   cursor  = rowptr + 10016;         // N
    int*   csr_src = cursor + 10016;         // E_total

    // ---- prep effective weights ----
    prep_kernel<<<256, 256, 0, stream>>>(W0, A0, B0, att_s0, att_d0, As0, Bs0, Ad0, Bd0,
                                         Weff0, effS0, effD0);
    prep_kernel<<<256, 256, 0, stream>>>(W1, A1, B1, att_s1, att_d1, As1, Bs1, Ad1, Bd1,
                                         Weff1, effS1, effD1);

    // ---- build CSR (per-destination in-edge lists) ----
    hipMemsetAsync(deg, 0, (size_t)N * sizeof(int), stream);
    hist_kernel<<<(E_total + 255) / 256, 256, 0, stream>>>(ei, E_real, E_total, deg);
    scan_kernel<<<1, 256, 0, stream>>>(deg, rowptr, cursor, N);
    fill_csr<<<(E_total + 255) / 256, 256, 0, stream>>>(ei, E_real, E_total, cursor, csr_src);

    dim3 gg(4, (N + GT - 1) / GT);
    int aggBlocks = (N * 64 + 255) / 256;

    // ---------------- layer 0 ----------------
    gemm_tn<<<gg, 256, 0, stream>>>(x, Weff0, xp, N);
    node_scores<<<(N * 8 + 255) / 256, 256, 0, stream>>>(xp, effS0, effD0, ssrc, sdst, N);
    csr_agg<<<aggBlocks, 256, 0, stream>>>(rowptr, csr_src, xp, ssrc, sdst, hb, N, 1);

    // ---------------- layer 1 ----------------
    gemm_tn<<<gg, 256, 0, stream>>>(hb, Weff1, xp, N);
    node_scores<<<(N * 8 + 255) / 256, 256, 0, stream>>>(xp, effS1, effD1, ssrc, sdst, N);
    csr_agg<<<aggBlocks, 256, 0, stream>>>(rowptr, csr_src, xp, ssrc, sdst, (float*)d_out, N, 2);
}

// Round 3
// 286.237 us; speedup vs baseline: 4.7822x; 1.1036x over previous
//
#include <hip/hip_runtime.h>

#define LORA_SCALE 4.0f
#define ATT_SCALE 8.0f
#define NEG_SLOPE 0.2f

typedef __attribute__((ext_vector_type(8))) short bf16x8;
typedef __attribute__((ext_vector_type(4))) float f32x4;
typedef unsigned short ushort_t;
typedef unsigned int uint_t;

__device__ inline ushort_t f2bf(float f) {
    uint_t u = __float_as_uint(f);
    u += 0x7fff + ((u >> 16) & 1);     // RNE
    return (ushort_t)(u >> 16);
}
__device__ inline float bf2f(ushort_t h) {
    return __uint_as_float(((uint_t)h) << 16);
}
__device__ inline void split_bf(float f, ushort_t& h, ushort_t& l) {
    h = f2bf(f);
    l = f2bf(f - bf2f(h));
}

// ---------- prep: Weff = W + LORA_SCALE*B@A -> bf16 hi/lo ; eff att vectors ----------
__global__ void prep_kernel(const float* __restrict__ W, const float* __restrict__ A,
                            const float* __restrict__ B,
                            const float* __restrict__ att_s, const float* __restrict__ att_d,
                            const float* __restrict__ As, const float* __restrict__ Bs,
                            const float* __restrict__ Ad, const float* __restrict__ Bd,
                            ushort_t* __restrict__ whi, ushort_t* __restrict__ wlo,
                            float* __restrict__ effS, float* __restrict__ effD)
{
    int i = blockIdx.x * blockDim.x + threadIdx.x;   // 65536 total
    int r = i >> 8, c = i & 255;
    float acc = W[i];
    #pragma unroll
    for (int k = 0; k < 8; k++) acc += LORA_SCALE * B[r * 8 + k] * A[k * 256 + c];
    ushort_t h, l;
    split_bf(acc, h, l);
    whi[i] = h; wlo[i] = l;
    if (i < 256) {
        int c2 = i & 31;
        float es = att_s[i], ed = att_d[i];
        #pragma unroll
        for (int k = 0; k < 4; k++) {
            es += ATT_SCALE * Bs[k] * As[k * 32 + c2];
            ed += ATT_SCALE * Bd[k] * Ad[k * 32 + c2];
        }
        effS[i] = es;
        effD[i] = ed;
    }
}

// ---------- convert x (fp32) -> bf16 hi/lo, 4 elems/thread ----------
__global__ void convert_x(const float* __restrict__ x, ushort_t* __restrict__ xhi,
                          ushort_t* __restrict__ xlo, int n4)
{
    int i = blockIdx.x * blockDim.x + threadIdx.x;
    if (i >= n4) return;
    float4 v = *(const float4*)(x + i * 4);
    ushort4 hs, ls;
    split_bf(v.x, hs.x, ls.x);
    split_bf(v.y, hs.y, ls.y);
    split_bf(v.z, hs.z, ls.z);
    split_bf(v.w, hs.w, ls.w);
    *(ushort4*)(xhi + i * 4) = hs;
    *(ushort4*)(xlo + i * 4) = ls;
}

// ---------- MFMA GEMM: C[m,n] = sum_k A[m,k]*W[n,k], hi/lo split (3 passes) ----------
// one wave per block: 16 rows x 64 cols. grid = (4, M/16)
__global__ __launch_bounds__(64) void gemm_mfma(
    const ushort_t* __restrict__ Ahi, const ushort_t* __restrict__ Alo,
    const ushort_t* __restrict__ Bhi, const ushort_t* __restrict__ Blo,
    float* __restrict__ C, int M)
{
    const int K = 256;
    int lane = threadIdx.x;
    int quad = lane >> 4;
    int l16 = lane & 15;
    int m0 = blockIdx.y * 16;
    int n0 = blockIdx.x * 64;
    int mr = m0 + l16; if (mr >= M) mr = M - 1;

    f32x4 acc[4] = {};
    #pragma unroll
    for (int seg = 0; seg < 3; seg++) {
        // C += [xhi*whi, xhi*wlo, xlo*whi]
        const ushort_t* Aseg = (seg == 2) ? Alo : Ahi;
        const ushort_t* Bseg = (seg == 1) ? Blo : Bhi;
        const ushort_t* arow = Aseg + mr * K + quad * 8;
        const ushort_t* brow = Bseg + (n0 + l16) * K + quad * 8;
        #pragma unroll
        for (int k0 = 0; k0 < K; k0 += 32) {
            bf16x8 a = *(const bf16x8*)(arow + k0);
            #pragma unroll
            for (int t = 0; t < 4; t++) {
                bf16x8 b = *(const bf16x8*)(brow + t * 16 * K + k0);
                acc[t] = __builtin_amdgcn_mfma_f32_16x16x32_bf16(a, b, acc[t], 0, 0, 0);
            }
        }
    }
    // C/D layout: col = lane&15, row = quad*4 + reg
    #pragma unroll
    for (int t = 0; t < 4; t++) {
        #pragma unroll
        for (int r = 0; r < 4; r++) {
            int m = m0 + quad * 4 + r;
            if (m < M) C[m * 256 + n0 + t * 16 + l16] = acc[t][r];
        }
    }
}

// ---------- per-node attention scores (vectorized) ----------
__global__ void node_scores(const float* __restrict__ xp,
                            const float* __restrict__ effS, const float* __restrict__ effD,
                            float* __restrict__ ssrc, float* __restrict__ sdst, int N)
{
    int idx = blockIdx.x * blockDim.x + threadIdx.x;  // N*8
    if (idx >= N * 8) return;
    int n = idx >> 3, h = idx & 7;
    const float4* v = (const float4*)(xp + n * 256 + h * 32);
    const float4* es = (const float4*)(effS + h * 32);
    const float4* ed = (const float4*)(effD + h * 32);
    float as = 0.f, ad = 0.f;
    #pragma unroll
    for (int c = 0; c < 8; c++) {
        float4 xv = v[c], e1 = es[c], e2 = ed[c];
        as += xv.x * e1.x + xv.y * e1.y + xv.z * e1.z + xv.w * e1.w;
        ad += xv.x * e2.x + xv.y * e2.y + xv.z * e2.z + xv.w * e2.w;
    }
    ssrc[idx] = as;
    sdst[idx] = ad;
}

// ---------- CSR build ----------
__global__ void hist_kernel(const int* __restrict__ ei, int E_real, int E_total,
                            int* __restrict__ deg)
{
    int e = blockIdx.x * blockDim.x + threadIdx.x;
    if (e >= E_total) return;
    int d = (e < E_real) ? ei[E_real + e] : (e - E_real);
    atomicAdd(&deg[d], 1);
}

__global__ __launch_bounds__(256) void scan_kernel(const int* __restrict__ deg,
                                                   int* __restrict__ rowptr,
                                                   int* __restrict__ cursor, int N)
{
    __shared__ int sums[256];
    int t = threadIdx.x;
    int per = (N + 255) / 256;
    int start = t * per;
    int end = start + per; if (end > N) end = N; if (start > N) start = N;
    int s = 0;
    for (int i = start; i < end; i++) s += deg[i];
    sums[t] = s;
    __syncthreads();
    for (int off = 1; off < 256; off <<= 1) {
        int v = (t >= off) ? sums[t - off] : 0;
        __syncthreads();
        sums[t] += v;
        __syncthreads();
    }
    int prefix = (t == 0) ? 0 : sums[t - 1];
    for (int i = start; i < end; i++) {
        rowptr[i] = prefix;
        cursor[i] = prefix;
        prefix += deg[i];
    }
    if (t == 255) rowptr[N] = sums[255];
}

__global__ void fill_csr(const int* __restrict__ ei, int E_real, int E_total,
                         int* __restrict__ cursor, int* __restrict__ csr_src)
{
    int e = blockIdx.x * blockDim.x + threadIdx.x;
    if (e >= E_total) return;
    int s, d;
    if (e < E_real) { s = ei[e]; d = ei[E_real + e]; }
    else            { s = d = e - E_real; }
    int pos = atomicAdd(&cursor[d], 1);
    csr_src[pos] = s;
}

// ---------- single-pass gather-aggregate: one wave per destination node ----------
// mode 1: ELU, write bf16 hi/lo 256ch; mode 2: head-mean -> 32ch fp32
__global__ __launch_bounds__(256) void csr_agg(const int* __restrict__ rowptr,
                                               const int* __restrict__ csr_src,
                                               const float* __restrict__ xp,
                                               const float* __restrict__ ssrc,
                                               const float* __restrict__ sdst,
                                               float* __restrict__ out,
                                               ushort_t* __restrict__ ohi,
                                               ushort_t* __restrict__ olo,
                                               int N, int mode)
{
    int gid = blockIdx.x * blockDim.x + threadIdx.x;
    int d = gid >> 6;
    if (d >= N) return;
    int lane = threadIdx.x & 63;
    int h = lane >> 3;                  // head for channels lane*4..lane*4+3
    float ssrc_h = ssrc[d * 8 + h];
    int begin = rowptr[d], end = rowptr[d + 1];

    float den = 0.f, ax = 0.f, ay = 0.f, az = 0.f, aw = 0.f;
    for (int i = begin; i < end; i++) {
        int s = csr_src[i];
        float al = ssrc_h + sdst[s * 8 + h];
        al = al > 0.f ? al : NEG_SLOPE * al;
        float w = __expf(al);
        den += w;
        const float4 v = *(const float4*)(xp + s * 256 + lane * 4);
        ax += v.x * w; ay += v.y * w; az += v.z * w; aw += v.w * w;
    }
    float inv = 1.f / den;
    ax *= inv; ay *= inv; az *= inv; aw *= inv;

    if (mode == 2) {
        #pragma unroll
        for (int m = 8; m <= 32; m <<= 1) {
            ax += __shfl_xor(ax, m);
            ay += __shfl_xor(ay, m);
            az += __shfl_xor(az, m);
            aw += __shfl_xor(aw, m);
        }
        if (lane < 8) {
            float4 r = { ax * 0.125f, ay * 0.125f, az * 0.125f, aw * 0.125f };
            *(float4*)(out + d * 32 + lane * 4) = r;
        }
        return;
    }
    // mode 1: ELU then bf16 hi/lo split
    ax = ax > 0.f ? ax : (__expf(ax) - 1.f);
    ay = ay > 0.f ? ay : (__expf(ay) - 1.f);
    az = az > 0.f ? az : (__expf(az) - 1.f);
    aw = aw > 0.f ? aw : (__expf(aw) - 1.f);
    ushort4 hs, ls;
    split_bf(ax, hs.x, ls.x);
    split_bf(ay, hs.y, ls.y);
    split_bf(az, hs.z, ls.z);
    split_bf(aw, hs.w, ls.w);
    *(ushort4*)(ohi + d * 256 + lane * 4) = hs;
    *(ushort4*)(olo + d * 256 + lane * 4) = ls;
}

extern "C" void kernel_launch(void* const* d_in, const int* in_sizes, int n_in,
                              void* d_out, int out_size, void* d_ws, size_t ws_size,
                              hipStream_t stream)
{
    const float* x  = (const float*)d_in[0];
    const int*   ei = (const int*)d_in[1];
    const float* W0 = (const float*)d_in[2];
    const float* A0 = (const float*)d_in[3];
    const float* B0 = (const float*)d_in[4];
    const float* att_s0 = (const float*)d_in[5];
    const float* att_d0 = (const float*)d_in[6];
    const float* As0 = (const float*)d_in[7];
    const float* Bs0 = (const float*)d_in[8];
    const float* Ad0 = (const float*)d_in[9];
    const float* Bd0 = (const float*)d_in[10];
    const float* W1 = (const float*)d_in[11];
    const float* A1 = (const float*)d_in[12];
    const float* B1 = (const float*)d_in[13];
    const float* att_s1 = (const float*)d_in[14];
    const float* att_d1 = (const float*)d_in[15];
    const float* As1 = (const float*)d_in[16];
    const float* Bs1 = (const float*)d_in[17];
    const float* Ad1 = (const float*)d_in[18];
    const float* Bd1 = (const float*)d_in[19];

    const int N = in_sizes[0] / 256;      // 10000
    const int E_real = in_sizes[1] / 2;   // 160000
    const int E_total = E_real + N;       // 170000

    // ---- workspace layout ----
    ushort_t* whi0 = (ushort_t*)d_ws;        // 65536
    ushort_t* wlo0 = whi0 + 65536;
    ushort_t* whi1 = wlo0 + 65536;
    ushort_t* wlo1 = whi1 + 65536;
    ushort_t* xhi  = wlo1 + 65536;           // N*256
    ushort_t* xlo  = xhi + 2560000;
    ushort_t* hbhi = xlo + 2560000;
    ushort_t* hblo = hbhi + 2560000;
    float* effS0 = (float*)(hblo + 2560000);
    float* effD0 = effS0 + 256;
    float* effS1 = effD0 + 256;
    float* effD1 = effS1 + 256;
    float* xp    = effD1 + 256;              // N*256
    float* ssrc  = xp + 2560000;             // N*8
    float* sdst  = ssrc + 80000;
    int* deg     = (int*)(sdst + 80000);
    int* rowptr  = deg + 10016;
    int* cursor  = rowptr + 10016;
    int* csr_src = cursor + 10016;           // E_total

    // ---- prep effective weights + x conversion + CSR build ----
    prep_kernel<<<256, 256, 0, stream>>>(W0, A0, B0, att_s0, att_d0, As0, Bs0, Ad0, Bd0,
                                         whi0, wlo0, effS0, effD0);
    prep_kernel<<<256, 256, 0, stream>>>(W1, A1, B1, att_s1, att_d1, As1, Bs1, Ad1, Bd1,
                                         whi1, wlo1, effS1, effD1);
    convert_x<<<(N * 64 + 255) / 256, 256, 0, stream>>>(x, xhi, xlo, N * 64);
    hipMemsetAsync(deg, 0, (size_t)N * sizeof(int), stream);
    hist_kernel<<<(E_total + 255) / 256, 256, 0, stream>>>(ei, E_real, E_total, deg);
    scan_kernel<<<1, 256, 0, stream>>>(deg, rowptr, cursor, N);
    fill_csr<<<(E_total + 255) / 256, 256, 0, stream>>>(ei, E_real, E_total, cursor, csr_src);

    dim3 gg(4, (N + 15) / 16);
    int aggBlocks = (N * 64 + 255) / 256;

    // ---------------- layer 0 ----------------
    gemm_mfma<<<gg, 64, 0, stream>>>(xhi, xlo, whi0, wlo0, xp, N);
    node_scores<<<(N * 8 + 255) / 256, 256, 0, stream>>>(xp, effS0, effD0, ssrc, sdst, N);
    csr_agg<<<aggBlocks, 256, 0, stream>>>(rowptr, csr_src, xp, ssrc, sdst,
                                           nullptr, hbhi, hblo, N, 1);

    // ---------------- layer 1 ----------------
    gemm_mfma<<<gg, 64, 0, stream>>>(hbhi, hblo, whi1, wlo1, xp, N);
    node_scores<<<(N * 8 + 255) / 256, 256, 0, stream>>>(xp, effS1, effD1, ssrc, sdst, N);
    csr_agg<<<aggBlocks, 256, 0, stream>>>(rowptr, csr_src, xp, ssrc, sdst,
                                           (float*)d_out, nullptr, nullptr, N, 2);
}

// Round 4
// 233.629 us; speedup vs baseline: 5.8591x; 1.2252x over previous
//
#include <hip/hip_runtime.h>

#define LORA_SCALE 4.0f
#define ATT_SCALE 8.0f
#define NEG_SLOPE 0.2f

typedef __attribute__((ext_vector_type(8))) short bf16x8;
typedef __attribute__((ext_vector_type(4))) float f32x4;
typedef unsigned short ushort_t;
typedef unsigned int uint_t;

__device__ inline ushort_t f2bf(float f) {
    uint_t u = __float_as_uint(f);
    u += 0x7fff + ((u >> 16) & 1);     // RNE
    return (ushort_t)(u >> 16);
}
__device__ inline float bf2f(ushort_t h) {
    return __uint_as_float(((uint_t)h) << 16);
}
__device__ inline void split_bf(float f, ushort_t& h, ushort_t& l) {
    h = f2bf(f);
    l = f2bf(f - bf2f(h));
}

// ---------- fused prep: weights(2 layers) + x->bf16 split + deg zero ----------
__global__ void prep_all(const float* __restrict__ W0, const float* __restrict__ A0,
                         const float* __restrict__ B0,
                         const float* __restrict__ att_s0, const float* __restrict__ att_d0,
                         const float* __restrict__ As0, const float* __restrict__ Bs0,
                         const float* __restrict__ Ad0, const float* __restrict__ Bd0,
                         const float* __restrict__ W1, const float* __restrict__ A1,
                         const float* __restrict__ B1,
                         const float* __restrict__ att_s1, const float* __restrict__ att_d1,
                         const float* __restrict__ As1, const float* __restrict__ Bs1,
                         const float* __restrict__ Ad1, const float* __restrict__ Bd1,
                         ushort_t* __restrict__ whi0, ushort_t* __restrict__ wlo0,
                         ushort_t* __restrict__ whi1, ushort_t* __restrict__ wlo1,
                         float* __restrict__ effS0, float* __restrict__ effD0,
                         float* __restrict__ effS1, float* __restrict__ effD1,
                         const float* __restrict__ x, ushort_t* __restrict__ xhi,
                         ushort_t* __restrict__ xlo, int* __restrict__ deg, int N)
{
    int b = blockIdx.x;
    int t = threadIdx.x;
    if (b < 512) {
        int layer = b >> 8;
        int i = (b & 255) * 256 + t;
        const float* W = layer ? W1 : W0;
        const float* A = layer ? A1 : A0;
        const float* B = layer ? B1 : B0;
        int r = i >> 8, c = i & 255;
        float acc = W[i];
        #pragma unroll
        for (int k = 0; k < 8; k++) acc += LORA_SCALE * B[r * 8 + k] * A[k * 256 + c];
        ushort_t h, l;
        split_bf(acc, h, l);
        if (layer) { whi1[i] = h; wlo1[i] = l; }
        else       { whi0[i] = h; wlo0[i] = l; }
        if (i < 256) {
            int c2 = i & 31;
            const float* as_ = layer ? att_s1 : att_s0;
            const float* ad_ = layer ? att_d1 : att_d0;
            const float* As = layer ? As1 : As0;
            const float* Bs = layer ? Bs1 : Bs0;
            const float* Ad = layer ? Ad1 : Ad0;
            const float* Bd = layer ? Bd1 : Bd0;
            float es = as_[i], ed = ad_[i];
            #pragma unroll
            for (int k = 0; k < 4; k++) {
                es += ATT_SCALE * Bs[k] * As[k * 32 + c2];
                ed += ATT_SCALE * Bd[k] * Ad[k * 32 + c2];
            }
            if (layer) { effS1[i] = es; effD1[i] = ed; }
            else       { effS0[i] = es; effD0[i] = ed; }
        }
        return;
    }
    int cb = b - 512;
    int convB = (N * 64 + 255) / 256;
    if (cb < convB) {
        int i = cb * 256 + t;
        if (i >= N * 64) return;
        float4 v = *(const float4*)(x + i * 4);
        ushort4 hs, ls;
        split_bf(v.x, hs.x, ls.x);
        split_bf(v.y, hs.y, ls.y);
        split_bf(v.z, hs.z, ls.z);
        split_bf(v.w, hs.w, ls.w);
        *(ushort4*)(xhi + i * 4) = hs;
        *(ushort4*)(xlo + i * 4) = ls;
        return;
    }
    int zi = (cb - convB) * 256 + t;
    if (zi < N) deg[zi] = 0;
}

// ---------- MFMA GEMM + fused attention scores ----------
// one wave per block: 16 rows x 64 cols (= 2 complete heads). grid = (4, M/16)
__global__ __launch_bounds__(64) void gemm_fused(
    const ushort_t* __restrict__ Ahi, const ushort_t* __restrict__ Alo,
    const ushort_t* __restrict__ Bhi, const ushort_t* __restrict__ Blo,
    const float* __restrict__ effS, const float* __restrict__ effD,
    float* __restrict__ C, float* __restrict__ ssrc, float* __restrict__ sdst, int M)
{
    const int K = 256;
    int lane = threadIdx.x;
    int quad = lane >> 4;
    int l16 = lane & 15;
    int m0 = blockIdx.y * 16;
    int n0 = blockIdx.x * 64;
    int mr = m0 + l16; if (mr >= M) mr = M - 1;

    const ushort_t* ah = Ahi + mr * K + quad * 8;
    const ushort_t* al = Alo + mr * K + quad * 8;
    const ushort_t* bh = Bhi + (n0 + l16) * K + quad * 8;
    const ushort_t* bl = Blo + (n0 + l16) * K + quad * 8;

    f32x4 acc[4] = {};
    #pragma unroll
    for (int k0 = 0; k0 < K; k0 += 32) {
        bf16x8 a_hi = *(const bf16x8*)(ah + k0);
        bf16x8 a_lo = *(const bf16x8*)(al + k0);
        #pragma unroll
        for (int t = 0; t < 4; t++) {
            bf16x8 b_hi = *(const bf16x8*)(bh + t * 16 * K + k0);
            bf16x8 b_lo = *(const bf16x8*)(bl + t * 16 * K + k0);
            acc[t] = __builtin_amdgcn_mfma_f32_16x16x32_bf16(a_hi, b_hi, acc[t], 0, 0, 0);
            acc[t] = __builtin_amdgcn_mfma_f32_16x16x32_bf16(a_hi, b_lo, acc[t], 0, 0, 0);
            acc[t] = __builtin_amdgcn_mfma_f32_16x16x32_bf16(a_lo, b_hi, acc[t], 0, 0, 0);
        }
    }

    // ---- store C: C/D layout col = l16, row = quad*4 + reg ----
    #pragma unroll
    for (int t = 0; t < 4; t++) {
        #pragma unroll
        for (int r = 0; r < 4; r++) {
            int m = m0 + quad * 4 + r;
            if (m < M) C[m * 256 + n0 + t * 16 + l16] = acc[t][r];
        }
    }

    // ---- fused scores: this block owns heads h0, h0+1 for rows m0..m0+15 ----
    int h0 = n0 >> 5;
    float vs[2][4], vd[2][4];
    #pragma unroll
    for (int g = 0; g < 2; g++) {
        float e0s = effS[n0 + 32 * g + l16];
        float e1s = effS[n0 + 32 * g + 16 + l16];
        float e0d = effD[n0 + 32 * g + l16];
        float e1d = effD[n0 + 32 * g + 16 + l16];
        #pragma unroll
        for (int r = 0; r < 4; r++) {
            vs[g][r] = acc[2 * g][r] * e0s + acc[2 * g + 1][r] * e1s;
            vd[g][r] = acc[2 * g][r] * e0d + acc[2 * g + 1][r] * e1d;
        }
    }
    #pragma unroll
    for (int m = 1; m <= 8; m <<= 1) {
        #pragma unroll
        for (int g = 0; g < 2; g++)
            #pragma unroll
            for (int r = 0; r < 4; r++) {
                vs[g][r] += __shfl_xor(vs[g][r], m);
                vd[g][r] += __shfl_xor(vd[g][r], m);
            }
    }
    if (l16 == 0) {
        #pragma unroll
        for (int g = 0; g < 2; g++)
            #pragma unroll
            for (int r = 0; r < 4; r++) {
                int m = m0 + quad * 4 + r;
                if (m < M) {
                    ssrc[m * 8 + h0 + g] = vs[g][r];
                    sdst[m * 8 + h0 + g] = vd[g][r];
                }
            }
    }
}

// ---------- CSR build ----------
__global__ void hist_kernel(const int* __restrict__ ei, int E_real, int E_total,
                            int* __restrict__ deg)
{
    int e = blockIdx.x * blockDim.x + threadIdx.x;
    if (e >= E_total) return;
    int d = (e < E_real) ? ei[E_real + e] : (e - E_real);
    atomicAdd(&deg[d], 1);
}

__global__ __launch_bounds__(1024) void scan_kernel(const int* __restrict__ deg,
                                                    int* __restrict__ rowptr,
                                                    int* __restrict__ cursor, int N)
{
    __shared__ int sums[1024];
    int t = threadIdx.x;
    int per = (N + 1023) / 1024;
    int start = t * per;
    int end = start + per; if (end > N) end = N; if (start > N) start = N;
    int s = 0;
    for (int i = start; i < end; i++) s += deg[i];
    sums[t] = s;
    __syncthreads();
    for (int off = 1; off < 1024; off <<= 1) {
        int v = (t >= off) ? sums[t - off] : 0;
        __syncthreads();
        sums[t] += v;
        __syncthreads();
    }
    int prefix = (t == 0) ? 0 : sums[t - 1];
    for (int i = start; i < end; i++) {
        rowptr[i] = prefix;
        cursor[i] = prefix;
        prefix += deg[i];
    }
    if (t == 1023) rowptr[N] = sums[1023];
}

__global__ void fill_csr(const int* __restrict__ ei, int E_real, int E_total,
                         int* __restrict__ cursor, int* __restrict__ csr_src)
{
    int e = blockIdx.x * blockDim.x + threadIdx.x;
    if (e >= E_total) return;
    int s, d;
    if (e < E_real) { s = ei[e]; d = ei[E_real + e]; }
    else            { s = d = e - E_real; }
    int pos = atomicAdd(&cursor[d], 1);
    csr_src[pos] = s;
}

// ---------- single-pass gather-aggregate, unroll-4: one wave per node ----------
// mode 1: ELU, write bf16 hi/lo 256ch; mode 2: head-mean -> 32ch fp32
__global__ __launch_bounds__(256) void csr_agg(const int* __restrict__ rowptr,
                                               const int* __restrict__ csr_src,
                                               const float* __restrict__ xp,
                                               const float* __restrict__ ssrc,
                                               const float* __restrict__ sdst,
                                               float* __restrict__ out,
                                               ushort_t* __restrict__ ohi,
                                               ushort_t* __restrict__ olo,
                                               int N, int mode)
{
    int gid = blockIdx.x * blockDim.x + threadIdx.x;
    int d = gid >> 6;
    if (d >= N) return;
    int lane = threadIdx.x & 63;
    int h = lane >> 3;
    float ssrc_h = ssrc[d * 8 + h];
    int begin = rowptr[d], end = rowptr[d + 1];

    float den = 0.f, ax = 0.f, ay = 0.f, az = 0.f, aw = 0.f;
    int i = begin;
    for (; i + 3 < end; i += 4) {
        int s0 = csr_src[i];
        int s1 = csr_src[i + 1];
        int s2 = csr_src[i + 2];
        int s3 = csr_src[i + 3];
        float t0 = sdst[s0 * 8 + h];
        float t1 = sdst[s1 * 8 + h];
        float t2 = sdst[s2 * 8 + h];
        float t3 = sdst[s3 * 8 + h];
        const float4 v0 = *(const float4*)(xp + s0 * 256 + lane * 4);
        const float4 v1 = *(const float4*)(xp + s1 * 256 + lane * 4);
        const float4 v2 = *(const float4*)(xp + s2 * 256 + lane * 4);
        const float4 v3 = *(const float4*)(xp + s3 * 256 + lane * 4);
        float a0 = ssrc_h + t0; a0 = a0 > 0.f ? a0 : NEG_SLOPE * a0;
        float a1 = ssrc_h + t1; a1 = a1 > 0.f ? a1 : NEG_SLOPE * a1;
        float a2 = ssrc_h + t2; a2 = a2 > 0.f ? a2 : NEG_SLOPE * a2;
        float a3 = ssrc_h + t3; a3 = a3 > 0.f ? a3 : NEG_SLOPE * a3;
        float w0 = __expf(a0), w1 = __expf(a1), w2 = __expf(a2), w3 = __expf(a3);
        den += (w0 + w1) + (w2 + w3);
        ax += v0.x * w0 + v1.x * w1 + v2.x * w2 + v3.x * w3;
        ay += v0.y * w0 + v1.y * w1 + v2.y * w2 + v3.y * w3;
        az += v0.z * w0 + v1.z * w1 + v2.z * w2 + v3.z * w3;
        aw += v0.w * w0 + v1.w * w1 + v2.w * w2 + v3.w * w3;
    }
    for (; i < end; i++) {
        int s = csr_src[i];
        float al = ssrc_h + sdst[s * 8 + h];
        al = al > 0.f ? al : NEG_SLOPE * al;
        float w = __expf(al);
        den += w;
        const float4 v = *(const float4*)(xp + s * 256 + lane * 4);
        ax += v.x * w; ay += v.y * w; az += v.z * w; aw += v.w * w;
    }
    float inv = 1.f / den;
    ax *= inv; ay *= inv; az *= inv; aw *= inv;

    if (mode == 2) {
        #pragma unroll
        for (int m = 8; m <= 32; m <<= 1) {
            ax += __shfl_xor(ax, m);
            ay += __shfl_xor(ay, m);
            az += __shfl_xor(az, m);
            aw += __shfl_xor(aw, m);
        }
        if (lane < 8) {
            float4 r = { ax * 0.125f, ay * 0.125f, az * 0.125f, aw * 0.125f };
            *(float4*)(out + d * 32 + lane * 4) = r;
        }
        return;
    }
    ax = ax > 0.f ? ax : (__expf(ax) - 1.f);
    ay = ay > 0.f ? ay : (__expf(ay) - 1.f);
    az = az > 0.f ? az : (__expf(az) - 1.f);
    aw = aw > 0.f ? aw : (__expf(aw) - 1.f);
    ushort4 hs, ls;
    split_bf(ax, hs.x, ls.x);
    split_bf(ay, hs.y, ls.y);
    split_bf(az, hs.z, ls.z);
    split_bf(aw, hs.w, ls.w);
    *(ushort4*)(ohi + d * 256 + lane * 4) = hs;
    *(ushort4*)(olo + d * 256 + lane * 4) = ls;
}

extern "C" void kernel_launch(void* const* d_in, const int* in_sizes, int n_in,
                              void* d_out, int out_size, void* d_ws, size_t ws_size,
                              hipStream_t stream)
{
    const float* x  = (const float*)d_in[0];
    const int*   ei = (const int*)d_in[1];
    const float* W0 = (const float*)d_in[2];
    const float* A0 = (const float*)d_in[3];
    const float* B0 = (const float*)d_in[4];
    const float* att_s0 = (const float*)d_in[5];
    const float* att_d0 = (const float*)d_in[6];
    const float* As0 = (const float*)d_in[7];
    const float* Bs0 = (const float*)d_in[8];
    const float* Ad0 = (const float*)d_in[9];
    const float* Bd0 = (const float*)d_in[10];
    const float* W1 = (const float*)d_in[11];
    const float* A1 = (const float*)d_in[12];
    const float* B1 = (const float*)d_in[13];
    const float* att_s1 = (const float*)d_in[14];
    const float* att_d1 = (const float*)d_in[15];
    const float* As1 = (const float*)d_in[16];
    const float* Bs1 = (const float*)d_in[17];
    const float* Ad1 = (const float*)d_in[18];
    const float* Bd1 = (const float*)d_in[19];

    const int N = in_sizes[0] / 256;      // 10000
    const int E_real = in_sizes[1] / 2;   // 160000
    const int E_total = E_real + N;       // 170000

    // ---- workspace layout ----
    ushort_t* whi0 = (ushort_t*)d_ws;        // 65536
    ushort_t* wlo0 = whi0 + 65536;
    ushort_t* whi1 = wlo0 + 65536;
    ushort_t* wlo1 = whi1 + 65536;
    ushort_t* xhi  = wlo1 + 65536;           // N*256
    ushort_t* xlo  = xhi + 2560000;
    ushort_t* hbhi = xlo + 2560000;
    ushort_t* hblo = hbhi + 2560000;
    float* effS0 = (float*)(hblo + 2560000);
    float* effD0 = effS0 + 256;
    float* effS1 = effD0 + 256;
    float* effD1 = effS1 + 256;
    float* xp    = effD1 + 256;              // N*256
    float* ssrc  = xp + 2560000;             // N*8
    float* sdst  = ssrc + 80000;
    int* deg     = (int*)(sdst + 80000);
    int* rowptr  = deg + 10016;
    int* cursor  = rowptr + 10016;
    int* csr_src = cursor + 10016;           // E_total

    // ---- fused prep (weights, x split, deg zero) + CSR build ----
    int convB = (N * 64 + 255) / 256;
    int zeroB = (N + 255) / 256;
    prep_all<<<512 + convB + zeroB, 256, 0, stream>>>(
        W0, A0, B0, att_s0, att_d0, As0, Bs0, Ad0, Bd0,
        W1, A1, B1, att_s1, att_d1, As1, Bs1, Ad1, Bd1,
        whi0, wlo0, whi1, wlo1, effS0, effD0, effS1, effD1,
        x, xhi, xlo, deg, N);
    hist_kernel<<<(E_total + 255) / 256, 256, 0, stream>>>(ei, E_real, E_total, deg);
    scan_kernel<<<1, 1024, 0, stream>>>(deg, rowptr, cursor, N);
    fill_csr<<<(E_total + 255) / 256, 256, 0, stream>>>(ei, E_real, E_total, cursor, csr_src);

    dim3 gg(4, (N + 15) / 16);
    int aggBlocks = (N * 64 + 255) / 256;

    // ---------------- layer 0 ----------------
    gemm_fused<<<gg, 64, 0, stream>>>(xhi, xlo, whi0, wlo0, effS0, effD0, xp, ssrc, sdst, N);
    csr_agg<<<aggBlocks, 256, 0, stream>>>(rowptr, csr_src, xp, ssrc, sdst,
                                           nullptr, hbhi, hblo, N, 1);

    // ---------------- layer 1 ----------------
    gemm_fused<<<gg, 64, 0, stream>>>(hbhi, hblo, whi1, wlo1, effS1, effD1, xp, ssrc, sdst, N);
    csr_agg<<<aggBlocks, 256, 0, stream>>>(rowptr, csr_src, xp, ssrc, sdst,
                                           (float*)d_out, nullptr, nullptr, N, 2);
}

// Round 5
// 231.894 us; speedup vs baseline: 5.9029x; 1.0075x over previous
//
#include <hip/hip_runtime.h>

#define LORA_SCALE 4.0f
#define ATT_SCALE 8.0f
#define NEG_SLOPE 0.2f

typedef __attribute__((ext_vector_type(8))) short bf16x8;
typedef __attribute__((ext_vector_type(4))) float f32x4;
typedef unsigned short ushort_t;
typedef unsigned int uint_t;

__device__ inline ushort_t f2bf(float f) {
    uint_t u = __float_as_uint(f);
    u += 0x7fff + ((u >> 16) & 1);     // RNE
    return (ushort_t)(u >> 16);
}
__device__ inline float bf2f(ushort_t h) {
    return __uint_as_float(((uint_t)h) << 16);
}
__device__ inline void split_bf(float f, ushort_t& h, ushort_t& l) {
    h = f2bf(f);
    l = f2bf(f - bf2f(h));
}

// ---------- fused prep: weights(2 layers) + x->bf16 split + deg zero ----------
__global__ void prep_all(const float* __restrict__ W0, const float* __restrict__ A0,
                         const float* __restrict__ B0,
                         const float* __restrict__ att_s0, const float* __restrict__ att_d0,
                         const float* __restrict__ As0, const float* __restrict__ Bs0,
                         const float* __restrict__ Ad0, const float* __restrict__ Bd0,
                         const float* __restrict__ W1, const float* __restrict__ A1,
                         const float* __restrict__ B1,
                         const float* __restrict__ att_s1, const float* __restrict__ att_d1,
                         const float* __restrict__ As1, const float* __restrict__ Bs1,
                         const float* __restrict__ Ad1, const float* __restrict__ Bd1,
                         ushort_t* __restrict__ whi0, ushort_t* __restrict__ wlo0,
                         ushort_t* __restrict__ whi1, ushort_t* __restrict__ wlo1,
                         float* __restrict__ effS0, float* __restrict__ effD0,
                         float* __restrict__ effS1, float* __restrict__ effD1,
                         const float* __restrict__ x, ushort_t* __restrict__ xhi,
                         ushort_t* __restrict__ xlo, int* __restrict__ deg, int N)
{
    int b = blockIdx.x;
    int t = threadIdx.x;
    if (b < 512) {
        int layer = b >> 8;
        int i = (b & 255) * 256 + t;
        const float* W = layer ? W1 : W0;
        const float* A = layer ? A1 : A0;
        const float* B = layer ? B1 : B0;
        int r = i >> 8, c = i & 255;
        float acc = W[i];
        #pragma unroll
        for (int k = 0; k < 8; k++) acc += LORA_SCALE * B[r * 8 + k] * A[k * 256 + c];
        ushort_t h, l;
        split_bf(acc, h, l);
        if (layer) { whi1[i] = h; wlo1[i] = l; }
        else       { whi0[i] = h; wlo0[i] = l; }
        if (i < 256) {
            int c2 = i & 31;
            const float* as_ = layer ? att_s1 : att_s0;
            const float* ad_ = layer ? att_d1 : att_d0;
            const float* As = layer ? As1 : As0;
            const float* Bs = layer ? Bs1 : Bs0;
            const float* Ad = layer ? Ad1 : Ad0;
            const float* Bd = layer ? Bd1 : Bd0;
            float es = as_[i], ed = ad_[i];
            #pragma unroll
            for (int k = 0; k < 4; k++) {
                es += ATT_SCALE * Bs[k] * As[k * 32 + c2];
                ed += ATT_SCALE * Bd[k] * Ad[k * 32 + c2];
            }
            if (layer) { effS1[i] = es; effD1[i] = ed; }
            else       { effS0[i] = es; effD0[i] = ed; }
        }
        return;
    }
    int cb = b - 512;
    int convB = (N * 64 + 255) / 256;
    if (cb < convB) {
        int i = cb * 256 + t;
        if (i >= N * 64) return;
        float4 v = *(const float4*)(x + i * 4);
        ushort4 hs, ls;
        split_bf(v.x, hs.x, ls.x);
        split_bf(v.y, hs.y, ls.y);
        split_bf(v.z, hs.z, ls.z);
        split_bf(v.w, hs.w, ls.w);
        *(ushort4*)(xhi + i * 4) = hs;
        *(ushort4*)(xlo + i * 4) = ls;
        return;
    }
    int zi = (cb - convB) * 256 + t;
    if (zi < N) deg[zi] = 0;
}

// ---------- MFMA GEMM + fused attention scores ----------
// one wave per block: 16 rows x 64 cols (= 2 complete heads). grid = (4, M/16)
__global__ __launch_bounds__(64) void gemm_fused(
    const ushort_t* __restrict__ Ahi, const ushort_t* __restrict__ Alo,
    const ushort_t* __restrict__ Bhi, const ushort_t* __restrict__ Blo,
    const float* __restrict__ effS, const float* __restrict__ effD,
    float* __restrict__ C, float* __restrict__ ssrc, float* __restrict__ sdst, int M)
{
    const int K = 256;
    int lane = threadIdx.x;
    int quad = lane >> 4;
    int l16 = lane & 15;
    int m0 = blockIdx.y * 16;
    int n0 = blockIdx.x * 64;
    int mr = m0 + l16; if (mr >= M) mr = M - 1;

    const ushort_t* ah = Ahi + mr * K + quad * 8;
    const ushort_t* al = Alo + mr * K + quad * 8;
    const ushort_t* bh = Bhi + (n0 + l16) * K + quad * 8;
    const ushort_t* bl = Blo + (n0 + l16) * K + quad * 8;

    f32x4 acc[4] = {};
    #pragma unroll
    for (int k0 = 0; k0 < K; k0 += 32) {
        bf16x8 a_hi = *(const bf16x8*)(ah + k0);
        bf16x8 a_lo = *(const bf16x8*)(al + k0);
        #pragma unroll
        for (int t = 0; t < 4; t++) {
            bf16x8 b_hi = *(const bf16x8*)(bh + t * 16 * K + k0);
            bf16x8 b_lo = *(const bf16x8*)(bl + t * 16 * K + k0);
            acc[t] = __builtin_amdgcn_mfma_f32_16x16x32_bf16(a_hi, b_hi, acc[t], 0, 0, 0);
            acc[t] = __builtin_amdgcn_mfma_f32_16x16x32_bf16(a_hi, b_lo, acc[t], 0, 0, 0);
            acc[t] = __builtin_amdgcn_mfma_f32_16x16x32_bf16(a_lo, b_hi, acc[t], 0, 0, 0);
        }
    }

    // ---- store C: C/D layout col = l16, row = quad*4 + reg ----
    #pragma unroll
    for (int t = 0; t < 4; t++) {
        #pragma unroll
        for (int r = 0; r < 4; r++) {
            int m = m0 + quad * 4 + r;
            if (m < M) C[m * 256 + n0 + t * 16 + l16] = acc[t][r];
        }
    }

    // ---- fused scores: this block owns heads h0, h0+1 for rows m0..m0+15 ----
    int h0 = n0 >> 5;
    float vs[2][4], vd[2][4];
    #pragma unroll
    for (int g = 0; g < 2; g++) {
        float e0s = effS[n0 + 32 * g + l16];
        float e1s = effS[n0 + 32 * g + 16 + l16];
        float e0d = effD[n0 + 32 * g + l16];
        float e1d = effD[n0 + 32 * g + 16 + l16];
        #pragma unroll
        for (int r = 0; r < 4; r++) {
            vs[g][r] = acc[2 * g][r] * e0s + acc[2 * g + 1][r] * e1s;
            vd[g][r] = acc[2 * g][r] * e0d + acc[2 * g + 1][r] * e1d;
        }
    }
    #pragma unroll
    for (int m = 1; m <= 8; m <<= 1) {
        #pragma unroll
        for (int g = 0; g < 2; g++)
            #pragma unroll
            for (int r = 0; r < 4; r++) {
                vs[g][r] += __shfl_xor(vs[g][r], m);
                vd[g][r] += __shfl_xor(vd[g][r], m);
            }
    }
    if (l16 == 0) {
        #pragma unroll
        for (int g = 0; g < 2; g++)
            #pragma unroll
            for (int r = 0; r < 4; r++) {
                int m = m0 + quad * 4 + r;
                if (m < M) {
                    ssrc[m * 8 + h0 + g] = vs[g][r];
                    sdst[m * 8 + h0 + g] = vd[g][r];
                }
            }
    }
}

// ---------- CSR build ----------
__global__ void hist_kernel(const int* __restrict__ ei, int E_real, int E_total,
                            int* __restrict__ deg)
{
    int e = blockIdx.x * blockDim.x + threadIdx.x;
    if (e >= E_total) return;
    int d = (e < E_real) ? ei[E_real + e] : (e - E_real);
    atomicAdd(&deg[d], 1);
}

__global__ __launch_bounds__(1024) void scan_kernel(const int* __restrict__ deg,
                                                    int* __restrict__ rowptr,
                                                    int* __restrict__ cursor, int N)
{
    __shared__ int sums[1024];
    int t = threadIdx.x;
    int per = (N + 1023) / 1024;
    int start = t * per;
    int end = start + per; if (end > N) end = N; if (start > N) start = N;
    int s = 0;
    for (int i = start; i < end; i++) s += deg[i];
    sums[t] = s;
    __syncthreads();
    for (int off = 1; off < 1024; off <<= 1) {
        int v = (t >= off) ? sums[t - off] : 0;
        __syncthreads();
        sums[t] += v;
        __syncthreads();
    }
    int prefix = (t == 0) ? 0 : sums[t - 1];
    for (int i = start; i < end; i++) {
        rowptr[i] = prefix;
        cursor[i] = prefix;
        prefix += deg[i];
    }
    if (t == 1023) rowptr[N] = sums[1023];
}

__global__ void fill_csr(const int* __restrict__ ei, int E_real, int E_total,
                         int* __restrict__ cursor, int* __restrict__ csr_src)
{
    int e = blockIdx.x * blockDim.x + threadIdx.x;
    if (e >= E_total) return;
    int s, d;
    if (e < E_real) { s = ei[e]; d = ei[E_real + e]; }
    else            { s = d = e - E_real; }
    int pos = atomicAdd(&cursor[d], 1);
    csr_src[pos] = s;
}

// ---------- single-pass gather-aggregate, predicated unroll-8 ----------
// one wave per node. mode 1: ELU -> bf16 hi/lo 256ch; mode 2: head-mean -> 32ch fp32
__global__ __launch_bounds__(256) void csr_agg(const int* __restrict__ rowptr,
                                               const int* __restrict__ csr_src,
                                               const float* __restrict__ xp,
                                               const float* __restrict__ ssrc,
                                               const float* __restrict__ sdst,
                                               float* __restrict__ out,
                                               ushort_t* __restrict__ ohi,
                                               ushort_t* __restrict__ olo,
                                               int N, int mode)
{
    int gid = blockIdx.x * blockDim.x + threadIdx.x;
    int d = gid >> 6;
    if (d >= N) return;
    int lane = threadIdx.x & 63;
    int h = lane >> 3;
    float ssrc_h = ssrc[d * 8 + h];
    int begin = rowptr[d], end = rowptr[d + 1];
    int lim = end - 1;                 // deg >= 1 (self-loop)

    float den = 0.f, ax = 0.f, ay = 0.f, az = 0.f, aw = 0.f;
    for (int i = begin; i < end; i += 8) {
        int idx[8];
        #pragma unroll
        for (int j = 0; j < 8; j++) {
            int ii = i + j;
            idx[j] = csr_src[ii < end ? ii : lim];
        }
        float t[8];
        #pragma unroll
        for (int j = 0; j < 8; j++) t[j] = sdst[idx[j] * 8 + h];
        float4 v[8];
        #pragma unroll
        for (int j = 0; j < 8; j++) v[j] = *(const float4*)(xp + idx[j] * 256 + lane * 4);
        float w[8];
        #pragma unroll
        for (int j = 0; j < 8; j++) {
            float al = ssrc_h + t[j];
            al = al > 0.f ? al : NEG_SLOPE * al;
            w[j] = (i + j < end) ? __expf(al) : 0.f;
        }
        #pragma unroll
        for (int j = 0; j < 8; j++) {
            den += w[j];
            ax += v[j].x * w[j];
            ay += v[j].y * w[j];
            az += v[j].z * w[j];
            aw += v[j].w * w[j];
        }
    }
    float inv = 1.f / den;
    ax *= inv; ay *= inv; az *= inv; aw *= inv;

    if (mode == 2) {
        #pragma unroll
        for (int m = 8; m <= 32; m <<= 1) {
            ax += __shfl_xor(ax, m);
            ay += __shfl_xor(ay, m);
            az += __shfl_xor(az, m);
            aw += __shfl_xor(aw, m);
        }
        if (lane < 8) {
            float4 r = { ax * 0.125f, ay * 0.125f, az * 0.125f, aw * 0.125f };
            *(float4*)(out + d * 32 + lane * 4) = r;
        }
        return;
    }
    ax = ax > 0.f ? ax : (__expf(ax) - 1.f);
    ay = ay > 0.f ? ay : (__expf(ay) - 1.f);
    az = az > 0.f ? az : (__expf(az) - 1.f);
    aw = aw > 0.f ? aw : (__expf(aw) - 1.f);
    ushort4 hs, ls;
    split_bf(ax, hs.x, ls.x);
    split_bf(ay, hs.y, ls.y);
    split_bf(az, hs.z, ls.z);
    split_bf(aw, hs.w, ls.w);
    *(ushort4*)(ohi + d * 256 + lane * 4) = hs;
    *(ushort4*)(olo + d * 256 + lane * 4) = ls;
}

extern "C" void kernel_launch(void* const* d_in, const int* in_sizes, int n_in,
                              void* d_out, int out_size, void* d_ws, size_t ws_size,
                              hipStream_t stream)
{
    const float* x  = (const float*)d_in[0];
    const int*   ei = (const int*)d_in[1];
    const float* W0 = (const float*)d_in[2];
    const float* A0 = (const float*)d_in[3];
    const float* B0 = (const float*)d_in[4];
    const float* att_s0 = (const float*)d_in[5];
    const float* att_d0 = (const float*)d_in[6];
    const float* As0 = (const float*)d_in[7];
    const float* Bs0 = (const float*)d_in[8];
    const float* Ad0 = (const float*)d_in[9];
    const float* Bd0 = (const float*)d_in[10];
    const float* W1 = (const float*)d_in[11];
    const float* A1 = (const float*)d_in[12];
    const float* B1 = (const float*)d_in[13];
    const float* att_s1 = (const float*)d_in[14];
    const float* att_d1 = (const float*)d_in[15];
    const float* As1 = (const float*)d_in[16];
    const float* Bs1 = (const float*)d_in[17];
    const float* Ad1 = (const float*)d_in[18];
    const float* Bd1 = (const float*)d_in[19];

    const int N = in_sizes[0] / 256;      // 10000
    const int E_real = in_sizes[1] / 2;   // 160000
    const int E_total = E_real + N;       // 170000

    // ---- workspace layout ----
    ushort_t* whi0 = (ushort_t*)d_ws;        // 65536
    ushort_t* wlo0 = whi0 + 65536;
    ushort_t* whi1 = wlo0 + 65536;
    ushort_t* wlo1 = whi1 + 65536;
    ushort_t* xhi  = wlo1 + 65536;           // N*256
    ushort_t* xlo  = xhi + 2560000;
    ushort_t* hbhi = xlo + 2560000;
    ushort_t* hblo = hbhi + 2560000;
    float* effS0 = (float*)(hblo + 2560000);
    float* effD0 = effS0 + 256;
    float* effS1 = effD0 + 256;
    float* effD1 = effS1 + 256;
    float* xp    = effD1 + 256;              // N*256
    float* ssrc  = xp + 2560000;             // N*8
    float* sdst  = ssrc + 80000;
    int* deg     = (int*)(sdst + 80000);
    int* rowptr  = deg + 10016;
    int* cursor  = rowptr + 10016;
    int* csr_src = cursor + 10016;           // E_total

    // ---- fused prep (weights, x split, deg zero) + CSR build ----
    int convB = (N * 64 + 255) / 256;
    int zeroB = (N + 255) / 256;
    prep_all<<<512 + convB + zeroB, 256, 0, stream>>>(
        W0, A0, B0, att_s0, att_d0, As0, Bs0, Ad0, Bd0,
        W1, A1, B1, att_s1, att_d1, As1, Bs1, Ad1, Bd1,
        whi0, wlo0, whi1, wlo1, effS0, effD0, effS1, effD1,
        x, xhi, xlo, deg, N);
    hist_kernel<<<(E_total + 255) / 256, 256, 0, stream>>>(ei, E_real, E_total, deg);
    scan_kernel<<<1, 1024, 0, stream>>>(deg, rowptr, cursor, N);
    fill_csr<<<(E_total + 255) / 256, 256, 0, stream>>>(ei, E_real, E_total, cursor, csr_src);

    dim3 gg(4, (N + 15) / 16);
    int aggBlocks = (N * 64 + 255) / 256;

    // ---------------- layer 0 ----------------
    gemm_fused<<<gg, 64, 0, stream>>>(xhi, xlo, whi0, wlo0, effS0, effD0, xp, ssrc, sdst, N);
    csr_agg<<<aggBlocks, 256, 0, stream>>>(rowptr, csr_src, xp, ssrc, sdst,
                                           nullptr, hbhi, hblo, N, 1);

    // ---------------- layer 1 ----------------
    gemm_fused<<<gg, 64, 0, stream>>>(hbhi, hblo, whi1, wlo1, effS1, effD1, xp, ssrc, sdst, N);
    csr_agg<<<aggBlocks, 256, 0, stream>>>(rowptr, csr_src, xp, ssrc, sdst,
                                           (float*)d_out, nullptr, nullptr, N, 2);
}